// Round 4
// baseline (153.652 us; speedup 1.0000x reference)
//
#include <hip/hip_runtime.h>

// rep config: E edges, D_IN = D_OUT = 4, M = 32 channels.
// out[e,o,m] = (sum_i basis[e,o,i] * nf[U[e],i,m]) * ew[e, (o==0?0:1), m]
//
// Structure (R1, 158us): 8 lanes per edge, each lane owns a float4 of 4
// channels; all loads/stores 16B/lane, coalesced within each 8-lane group.
// R3 (+4%): nontemporal stores on the 410 MB write-only output stream.
// R4 single change: nontemporal LOADS on basis (51 MB) and ew (205 MB) —
// both single-use streams. Only the node_features gather table (25.6 MB,
// reused ~16x; 410 MB of request volume) keeps normal caching, so L2/L3
// retain it instead of being thrashed by the streams. Without this, the
// traffic arithmetic says gather re-fetches ~400 MB from HBM:
// (695 + 410) MB / 152 us = 7.3 TB/s = the fill-kernel HBM ceiling.

typedef float f4 __attribute__((ext_vector_type(4)));

__global__ __launch_bounds__(256) void equiv_mm_kernel(
    const float* __restrict__ basis,   // [E,4,4]
    const float* __restrict__ ew,      // [E,2,32]
    const float* __restrict__ nf,      // [N,4,32]
    const int*   __restrict__ U,       // [E]
    float*       __restrict__ out,     // [E,4,32]
    int E)
{
    int gid = blockIdx.x * blockDim.x + threadIdx.x;
    int e = gid >> 3;
    if (e >= E) return;
    int m0 = (gid & 7) << 2;   // channel offset: 0,4,...,28

    int u = U[e];

    // gather source-node features: rows i=0..3, stride 32 floats (=8 f4)
    // NORMAL loads -> allowed to stay cached (the only reused data)
    const f4* xp = (const f4*)(nf + (size_t)u * 128 + m0);
    f4 x0 = xp[0];
    f4 x1 = xp[8];
    f4 x2 = xp[16];
    f4 x3 = xp[24];

    // per-edge 4x4 basis (broadcast across the 8 lanes of this edge),
    // single-use stream -> nontemporal
    const f4* bp = (const f4*)(basis + (size_t)e * 16);
    f4 b0 = __builtin_nontemporal_load(bp + 0);
    f4 b1 = __builtin_nontemporal_load(bp + 1);
    f4 b2 = __builtin_nontemporal_load(bp + 2);
    f4 b3 = __builtin_nontemporal_load(bp + 3);

    // radial weights, single-use stream -> nontemporal
    const f4* wp = (const f4*)(ew + (size_t)e * 64 + m0);
    f4 w0 = __builtin_nontemporal_load(wp + 0);
    f4 w1 = __builtin_nontemporal_load(wp + 8);

    // write-only output stream -> nontemporal (no L2 allocate)
    f4* op = (f4*)(out + (size_t)e * 128 + m0);
    __builtin_nontemporal_store((b0.x * x0 + b0.y * x1 + b0.z * x2 + b0.w * x3) * w0, op + 0);
    __builtin_nontemporal_store((b1.x * x0 + b1.y * x1 + b1.z * x2 + b1.w * x3) * w1, op + 8);
    __builtin_nontemporal_store((b2.x * x0 + b2.y * x1 + b2.z * x2 + b2.w * x3) * w1, op + 16);
    __builtin_nontemporal_store((b3.x * x0 + b3.y * x1 + b3.z * x2 + b3.w * x3) * w1, op + 24);
}

extern "C" void kernel_launch(void* const* d_in, const int* in_sizes, int n_in,
                              void* d_out, int out_size, void* d_ws, size_t ws_size,
                              hipStream_t stream) {
    const float* basis = (const float*)d_in[0];   // [E,4,4]
    const float* ew    = (const float*)d_in[1];   // [E,2,32]
    const float* nf    = (const float*)d_in[2];   // [N,4,32]
    const int*   U     = (const int*)d_in[3];     // [E]
    float* out = (float*)d_out;

    int E = in_sizes[0] / 16;
    long long total = (long long)E * 8;           // 8 lanes per edge
    int block = 256;
    int grid = (int)((total + block - 1) / block);

    equiv_mm_kernel<<<grid, block, 0, stream>>>(basis, ew, nf, U, out, E);
}